// Round 1
// baseline (897.063 us; speedup 1.0000x reference)
//
#include <hip/hip_runtime.h>
#include <hip/hip_bf16.h>

#define N_NODES  100000
#define N_EDGES  1600000
#define D_FEAT   128
#define N_GRAPHS 128
#define N_CLS    10
#define CAP      64

typedef __bf16 bf16x8 __attribute__((ext_vector_type(8)));
typedef __bf16 bf16x2 __attribute__((ext_vector_type(2)));
typedef float  f32x4  __attribute__((ext_vector_type(4)));

// ---------------- W transpose + bf16 convert (Wt[n][k]) ----------------
__global__ __launch_bounds__(256) void prepW(const float* __restrict__ W0,
                                             const float* __restrict__ W1,
                                             const float* __restrict__ W2,
                                             __bf16* __restrict__ wt) {
    int idx = blockIdx.x * 256 + threadIdx.x;
    if (idx >= 3 * 16384) return;
    int which = idx >> 14, e = idx & 16383;
    int k = e >> 7, n = e & 127;
    const float* W = (which == 0) ? W0 : ((which == 1) ? W1 : W2);
    wt[which * 16384 + n * 128 + k] = (__bf16)W[k * 128 + n];
}

// ---------------- edge pass: count in-degree + bucket src lists ----------------
__global__ __launch_bounds__(256) void fill_edges(const int* __restrict__ ei,
                                                  int* __restrict__ cnt,
                                                  int* __restrict__ srclist) {
    int e = blockIdx.x * 256 + threadIdx.x;
    if (e >= N_EDGES) return;
    int src = ei[e];
    int dst = ei[N_EDGES + e];
    int p = atomicAdd(&cnt[dst], 1);
    if (p < CAP) srclist[dst * CAP + p] = src;
}

__global__ __launch_bounds__(256) void dinv_kernel(const int* __restrict__ cnt,
                                                   float* __restrict__ dinv) {
    int i = blockIdx.x * 256 + threadIdx.x;
    if (i >= N_NODES) return;
    dinv[i] = rsqrtf((float)cnt[i] + 1.0f);
}

// ---------------- GEMM: H[100000,128] = A[100000,128] @ W[128,128], bf16 MFMA ----------------
// One wave = 16 rows x 128 cols. Wt is column-major W (Wt[n][k]) in bf16.
template <bool A_IS_F32>
__global__ __launch_bounds__(256) void gemm128(const void* __restrict__ Ap,
                                               const __bf16* __restrict__ Wt,
                                               __bf16* __restrict__ H) {
    int wid = (blockIdx.x * 256 + threadIdx.x) >> 6;
    if (wid >= N_NODES / 16) return;   // 6250 waves exactly
    int lane = threadIdx.x & 63;
    int m = lane & 15, q = lane >> 4;
    int rowbase = wid * 16;

    f32x4 acc[8] = {};

#pragma unroll
    for (int ks = 0; ks < 4; ++ks) {
        bf16x8 a;
        if (A_IS_F32) {
            const float* A = (const float*)Ap + (size_t)(rowbase + m) * 128 + ks * 32 + q * 8;
            f32x4 v0 = *(const f32x4*)A;
            f32x4 v1 = *(const f32x4*)(A + 4);
            a[0] = (__bf16)v0[0]; a[1] = (__bf16)v0[1];
            a[2] = (__bf16)v0[2]; a[3] = (__bf16)v0[3];
            a[4] = (__bf16)v1[0]; a[5] = (__bf16)v1[1];
            a[6] = (__bf16)v1[2]; a[7] = (__bf16)v1[3];
        } else {
            a = *(const bf16x8*)((const __bf16*)Ap + (size_t)(rowbase + m) * 128 + ks * 32 + q * 8);
        }
#pragma unroll
        for (int tj = 0; tj < 8; ++tj) {
            bf16x8 b = *(const bf16x8*)(Wt + (tj * 16 + m) * 128 + ks * 32 + q * 8);
            acc[tj] = __builtin_amdgcn_mfma_f32_16x16x32_bf16(a, b, acc[tj], 0, 0, 0);
        }
    }

    // C/D layout: col = lane&15, row = (lane>>4)*4 + reg
#pragma unroll
    for (int tj = 0; tj < 8; ++tj) {
#pragma unroll
        for (int r = 0; r < 4; ++r) {
            int row = rowbase + q * 4 + r;
            H[(size_t)row * 128 + tj * 16 + m] = (__bf16)acc[tj][r];
        }
    }
}

// ---------------- aggregation: one wave per dst node, register accumulate ----------------
template <bool RELU>
__global__ __launch_bounds__(256) void aggregate(const __bf16* __restrict__ H,
                                                 const float* __restrict__ bias,
                                                 const float* __restrict__ dinv,
                                                 const int* __restrict__ cnt,
                                                 const int* __restrict__ srclist,
                                                 __bf16* __restrict__ X) {
    int node = blockIdx.x * 4 + (threadIdx.x >> 6);   // 25000 blocks * 4 waves = 100000
    int lane = threadIdx.x & 63;
    float di = dinv[node];
    int deg = cnt[node];
    if (deg > CAP) deg = CAP;

    bf16x2 hv = *(const bf16x2*)(H + (size_t)node * 128 + lane * 2);
    float2 bb = *(const float2*)(bias + lane * 2);
    float ax = bb.x + di * di * (float)hv[0];
    float ay = bb.y + di * di * (float)hv[1];

    const int* lst = srclist + (size_t)node * CAP;
    for (int e = 0; e < deg; ++e) {
        int s = lst[e];
        float f = di * dinv[s];
        bf16x2 v = *(const bf16x2*)(H + (size_t)s * 128 + lane * 2);
        ax += f * (float)v[0];
        ay += f * (float)v[1];
    }
    if (RELU) { ax = fmaxf(ax, 0.f); ay = fmaxf(ay, 0.f); }
    bf16x2 o; o[0] = (__bf16)ax; o[1] = (__bf16)ay;
    *(bf16x2*)(X + (size_t)node * 128 + lane * 2) = o;
}

// ---------------- mean-pool per graph + linear + softmax ----------------
__global__ __launch_bounds__(256) void pool_head(const __bf16* __restrict__ X,
                                                 const int* __restrict__ batch,
                                                 const float* __restrict__ linW,
                                                 const float* __restrict__ linb,
                                                 float* __restrict__ out) {
    __shared__ int bounds[2];
    __shared__ float red[256];
    __shared__ float pooled[128];
    int g = blockIdx.x, t = threadIdx.x;
    if (t < 2) {
        int target = g + t;
        int lo = 0, hi = N_NODES;
        while (lo < hi) {
            int mid = (lo + hi) >> 1;
            if (batch[mid] < target) lo = mid + 1; else hi = mid;
        }
        bounds[t] = lo;
    }
    __syncthreads();
    int start = bounds[0], end = bounds[1];
    int d = t & 127, half = t >> 7;
    float s = 0.f;
    for (int i = start + half; i < end; i += 2)
        s += (float)X[(size_t)i * 128 + d];
    red[t] = s;
    __syncthreads();
    if (t < 128) {
        float c = (float)(end - start);
        pooled[d] = (red[t] + red[t + 128]) / fmaxf(c, 1.f);
    }
    __syncthreads();
    if (t == 0) {
        float lg[N_CLS];
        float mx = -1e30f;
        for (int c = 0; c < N_CLS; ++c) {
            float l = linb[c];
            for (int k = 0; k < 128; ++k) l += pooled[k] * linW[k * N_CLS + c];
            lg[c] = l;
            mx = fmaxf(mx, l);
        }
        float ssum = 0.f;
        for (int c = 0; c < N_CLS; ++c) { lg[c] = expf(lg[c] - mx); ssum += lg[c]; }
        for (int c = 0; c < N_CLS; ++c) out[g * N_CLS + c] = lg[c] / ssum;
    }
}

extern "C" void kernel_launch(void* const* d_in, const int* in_sizes, int n_in,
                              void* d_out, int out_size, void* d_ws, size_t ws_size,
                              hipStream_t stream) {
    const float* x     = (const float*)d_in[0];
    const int*   ei    = (const int*)d_in[1];
    const int*   batch = (const int*)d_in[2];
    const float* W0    = (const float*)d_in[3];
    const float* b0    = (const float*)d_in[4];
    const float* W1    = (const float*)d_in[5];
    const float* b1    = (const float*)d_in[6];
    const float* W2    = (const float*)d_in[7];
    const float* b2    = (const float*)d_in[8];
    const float* linW  = (const float*)d_in[9];
    const float* linb  = (const float*)d_in[10];

    char* ws = (char*)d_ws;
    int*    cnt     = (int*)(ws + 0);          // 400000 B
    float*  dinv    = (float*)(ws + 400384);   // 400000 B
    __bf16* wt      = (__bf16*)(ws + 800768);  // 3*32768 B
    int*    srclist = (int*)(ws + 899584);     // 25.6 MB
    __bf16* hbuf    = (__bf16*)(ws + 26500096);// 25.6 MB
    __bf16* xbuf    = (__bf16*)(ws + 52100608);// 25.6 MB  (total ~77.7 MB)

    hipMemsetAsync(cnt, 0, N_NODES * sizeof(int), stream);

    prepW<<<192, 256, 0, stream>>>(W0, W1, W2, wt);
    fill_edges<<<N_EDGES / 256, 256, 0, stream>>>(ei, cnt, srclist);
    dinv_kernel<<<(N_NODES + 255) / 256, 256, 0, stream>>>(cnt, dinv);

    // Layer 0
    gemm128<true><<<1563, 256, 0, stream>>>(x, wt, hbuf);
    aggregate<true><<<N_NODES / 4, 256, 0, stream>>>(hbuf, b0, dinv, cnt, srclist, xbuf);
    // Layer 1
    gemm128<false><<<1563, 256, 0, stream>>>(xbuf, wt + 16384, hbuf);
    aggregate<true><<<N_NODES / 4, 256, 0, stream>>>(hbuf, b1, dinv, cnt, srclist, xbuf);
    // Layer 2 (no relu)
    gemm128<false><<<1563, 256, 0, stream>>>(xbuf, wt + 32768, hbuf);
    aggregate<false><<<N_NODES / 4, 256, 0, stream>>>(hbuf, b2, dinv, cnt, srclist, xbuf);

    pool_head<<<N_GRAPHS, 256, 0, stream>>>(xbuf, batch, linW, linb, (float*)d_out);
}

// Round 2
// 703.480 us; speedup vs baseline: 1.2752x; 1.2752x over previous
//
#include <hip/hip_runtime.h>
#include <hip/hip_bf16.h>

#define N_NODES  100000
#define N_EDGES  1600000
#define D_FEAT   128
#define N_GRAPHS 128
#define N_CLS    10
#define CAP      64

typedef __bf16 bf16x8 __attribute__((ext_vector_type(8)));
typedef __bf16 bf16x2 __attribute__((ext_vector_type(2)));
typedef float  f32x4  __attribute__((ext_vector_type(4)));

// ---------------- W transpose + bf16 convert (Wt[n][k]) ----------------
__global__ __launch_bounds__(256) void prepW(const float* __restrict__ W0,
                                             const float* __restrict__ W1,
                                             const float* __restrict__ W2,
                                             __bf16* __restrict__ wt) {
    int idx = blockIdx.x * 256 + threadIdx.x;
    if (idx >= 3 * 16384) return;
    int which = idx >> 14, e = idx & 16383;
    int k = e >> 7, n = e & 127;
    const float* W = (which == 0) ? W0 : ((which == 1) ? W1 : W2);
    wt[which * 16384 + n * 128 + k] = (__bf16)W[k * 128 + n];
}

// ---------------- edge pass: count in-degree + bucket src lists ----------------
__global__ __launch_bounds__(256) void fill_edges(const int* __restrict__ ei,
                                                  int* __restrict__ cnt,
                                                  int* __restrict__ srclist) {
    int e = blockIdx.x * 256 + threadIdx.x;
    if (e >= N_EDGES) return;
    int src = ei[e];
    int dst = ei[N_EDGES + e];
    int p = atomicAdd(&cnt[dst], 1);
    if (p < CAP) srclist[dst * CAP + p] = src;
}

__global__ __launch_bounds__(256) void dinv_kernel(const int* __restrict__ cnt,
                                                   float* __restrict__ dinv) {
    int i = blockIdx.x * 256 + threadIdx.x;
    if (i >= N_NODES) return;
    dinv[i] = rsqrtf((float)cnt[i] + 1.0f);
}

// ---------------- GEMM: H[100000,128] = A[100000,128] @ W[128,128], bf16 MFMA ----------------
template <bool A_IS_F32>
__global__ __launch_bounds__(256) void gemm128(const void* __restrict__ Ap,
                                               const __bf16* __restrict__ Wt,
                                               __bf16* __restrict__ H) {
    int wid = (blockIdx.x * 256 + threadIdx.x) >> 6;
    if (wid >= N_NODES / 16) return;   // 6250 waves exactly
    int lane = threadIdx.x & 63;
    int m = lane & 15, q = lane >> 4;
    int rowbase = wid * 16;

    f32x4 acc[8] = {};

#pragma unroll
    for (int ks = 0; ks < 4; ++ks) {
        bf16x8 a;
        if (A_IS_F32) {
            const float* A = (const float*)Ap + (size_t)(rowbase + m) * 128 + ks * 32 + q * 8;
            f32x4 v0 = *(const f32x4*)A;
            f32x4 v1 = *(const f32x4*)(A + 4);
            a[0] = (__bf16)v0[0]; a[1] = (__bf16)v0[1];
            a[2] = (__bf16)v0[2]; a[3] = (__bf16)v0[3];
            a[4] = (__bf16)v1[0]; a[5] = (__bf16)v1[1];
            a[6] = (__bf16)v1[2]; a[7] = (__bf16)v1[3];
        } else {
            a = *(const bf16x8*)((const __bf16*)Ap + (size_t)(rowbase + m) * 128 + ks * 32 + q * 8);
        }
#pragma unroll
        for (int tj = 0; tj < 8; ++tj) {
            bf16x8 b = *(const bf16x8*)(Wt + (tj * 16 + m) * 128 + ks * 32 + q * 8);
            acc[tj] = __builtin_amdgcn_mfma_f32_16x16x32_bf16(a, b, acc[tj], 0, 0, 0);
        }
    }

    // C/D layout: col = lane&15, row = (lane>>4)*4 + reg
#pragma unroll
    for (int tj = 0; tj < 8; ++tj) {
#pragma unroll
        for (int r = 0; r < 4; ++r) {
            int row = rowbase + q * 4 + r;
            H[(size_t)row * 128 + tj * 16 + m] = (__bf16)acc[tj][r];
        }
    }
}

// ---------------- aggregation: one wave per dst node, 4 edges/iter ----------------
// lanes: g = lane>>4 (edge slot 0..3), idx = lane&15 (dims idx*8 .. idx*8+7, 16B/lane)
template <bool RELU>
__global__ __launch_bounds__(256) void aggregate(const __bf16* __restrict__ H,
                                                 const float* __restrict__ bias,
                                                 const float* __restrict__ dinv,
                                                 const int* __restrict__ cnt,
                                                 const int* __restrict__ srclist,
                                                 __bf16* __restrict__ X) {
    int node = blockIdx.x * 4 + (threadIdx.x >> 6);   // 25000 blocks * 4 waves
    int lane = threadIdx.x & 63;
    int g = lane >> 4;
    int idx = lane & 15;
    float di = dinv[node];
    int deg = cnt[node];
    if (deg > CAP) deg = CAP;
    const int* lst = srclist + (size_t)node * CAP;

    float acc[8] = {0.f, 0.f, 0.f, 0.f, 0.f, 0.f, 0.f, 0.f};

    for (int e = 0; e < deg; e += 4) {
        int ee = e + g;
        bool act = ee < deg;
        int s = lst[act ? ee : e];           // in-bounds dummy for inactive slots
        float f = act ? di * dinv[s] : 0.f;
        bf16x8 v = *(const bf16x8*)(H + (size_t)s * 128 + idx * 8);
#pragma unroll
        for (int j = 0; j < 8; ++j) acc[j] += f * (float)v[j];
    }

    // reduce across the 4 edge-groups (lane bits 4,5)
#pragma unroll
    for (int j = 0; j < 8; ++j) {
        acc[j] += __shfl_xor(acc[j], 16);
        acc[j] += __shfl_xor(acc[j], 32);
    }

    // self-loop + bias + activation
    bf16x8 hv = *(const bf16x8*)(H + (size_t)node * 128 + idx * 8);
    f32x4 b0 = *(const f32x4*)(bias + idx * 8);
    f32x4 b1 = *(const f32x4*)(bias + idx * 8 + 4);
    float dii = di * di;
    bf16x8 o;
#pragma unroll
    for (int j = 0; j < 8; ++j) {
        float bj = (j < 4) ? b0[j] : b1[j - 4];
        float t = acc[j] + dii * (float)hv[j] + bj;
        if (RELU) t = fmaxf(t, 0.f);
        o[j] = (__bf16)t;
    }
    if (g == 0) *(bf16x8*)(X + (size_t)node * 128 + idx * 8) = o;
}

// ---------------- mean-pool per graph + linear + softmax ----------------
__global__ __launch_bounds__(256) void pool_head(const __bf16* __restrict__ X,
                                                 const int* __restrict__ batch,
                                                 const float* __restrict__ linW,
                                                 const float* __restrict__ linb,
                                                 float* __restrict__ out) {
    __shared__ int bounds[2];
    __shared__ float red[256];
    __shared__ float pooled[128];
    int g = blockIdx.x, t = threadIdx.x;
    if (t < 2) {
        int target = g + t;
        int lo = 0, hi = N_NODES;
        while (lo < hi) {
            int mid = (lo + hi) >> 1;
            if (batch[mid] < target) lo = mid + 1; else hi = mid;
        }
        bounds[t] = lo;
    }
    __syncthreads();
    int start = bounds[0], end = bounds[1];
    int d = t & 127, half = t >> 7;
    float s = 0.f;
    for (int i = start + half; i < end; i += 2)
        s += (float)X[(size_t)i * 128 + d];
    red[t] = s;
    __syncthreads();
    if (t < 128) {
        float c = (float)(end - start);
        pooled[d] = (red[t] + red[t + 128]) / fmaxf(c, 1.f);
    }
    __syncthreads();
    if (t == 0) {
        float lg[N_CLS];
        float mx = -1e30f;
        for (int c = 0; c < N_CLS; ++c) {
            float l = linb[c];
            for (int k = 0; k < 128; ++k) l += pooled[k] * linW[k * N_CLS + c];
            lg[c] = l;
            mx = fmaxf(mx, l);
        }
        float ssum = 0.f;
        for (int c = 0; c < N_CLS; ++c) { lg[c] = expf(lg[c] - mx); ssum += lg[c]; }
        for (int c = 0; c < N_CLS; ++c) out[g * N_CLS + c] = lg[c] / ssum;
    }
}

extern "C" void kernel_launch(void* const* d_in, const int* in_sizes, int n_in,
                              void* d_out, int out_size, void* d_ws, size_t ws_size,
                              hipStream_t stream) {
    const float* x     = (const float*)d_in[0];
    const int*   ei    = (const int*)d_in[1];
    const int*   batch = (const int*)d_in[2];
    const float* W0    = (const float*)d_in[3];
    const float* b0    = (const float*)d_in[4];
    const float* W1    = (const float*)d_in[5];
    const float* b1    = (const float*)d_in[6];
    const float* W2    = (const float*)d_in[7];
    const float* b2    = (const float*)d_in[8];
    const float* linW  = (const float*)d_in[9];
    const float* linb  = (const float*)d_in[10];

    char* ws = (char*)d_ws;
    int*    cnt     = (int*)(ws + 0);          // 400000 B
    float*  dinv    = (float*)(ws + 400384);   // 400000 B
    __bf16* wt      = (__bf16*)(ws + 800768);  // 3*32768 B
    int*    srclist = (int*)(ws + 899584);     // 25.6 MB
    __bf16* hbuf    = (__bf16*)(ws + 26500096);// 25.6 MB
    __bf16* xbuf    = (__bf16*)(ws + 52100608);// 25.6 MB

    hipMemsetAsync(cnt, 0, N_NODES * sizeof(int), stream);

    prepW<<<192, 256, 0, stream>>>(W0, W1, W2, wt);
    fill_edges<<<N_EDGES / 256, 256, 0, stream>>>(ei, cnt, srclist);
    dinv_kernel<<<(N_NODES + 255) / 256, 256, 0, stream>>>(cnt, dinv);

    // Layer 0
    gemm128<true><<<1563, 256, 0, stream>>>(x, wt, hbuf);
    aggregate<true><<<N_NODES / 4, 256, 0, stream>>>(hbuf, b0, dinv, cnt, srclist, xbuf);
    // Layer 1
    gemm128<false><<<1563, 256, 0, stream>>>(xbuf, wt + 16384, hbuf);
    aggregate<true><<<N_NODES / 4, 256, 0, stream>>>(hbuf, b1, dinv, cnt, srclist, xbuf);
    // Layer 2 (no relu)
    gemm128<false><<<1563, 256, 0, stream>>>(xbuf, wt + 32768, hbuf);
    aggregate<false><<<N_NODES / 4, 256, 0, stream>>>(hbuf, b2, dinv, cnt, srclist, xbuf);

    pool_head<<<N_GRAPHS, 256, 0, stream>>>(xbuf, batch, linW, linb, (float*)d_out);
}

// Round 3
// 603.406 us; speedup vs baseline: 1.4867x; 1.1658x over previous
//
#include <hip/hip_runtime.h>
#include <hip/hip_bf16.h>

#define N_NODES  100000
#define N_EDGES  1600000
#define D_FEAT   128
#define N_GRAPHS 128
#define N_CLS    10
#define CAP      64

#define NB       391      // buckets of 256 dst nodes (391*256 = 100096)
#define CAPB     4608     // staging capacity per bucket (mean 4096, +8 sigma)
#define CHUNK    8000     // edges per binsort block (200 * 8000 = 1.6M)

typedef __bf16 bf16x8 __attribute__((ext_vector_type(8)));
typedef __bf16 bf16x2 __attribute__((ext_vector_type(2)));
typedef float  f32x4  __attribute__((ext_vector_type(4)));

// ---------------- W transpose + bf16 convert (Wt[n][k]) ----------------
__global__ __launch_bounds__(256) void prepW(const float* __restrict__ W0,
                                             const float* __restrict__ W1,
                                             const float* __restrict__ W2,
                                             __bf16* __restrict__ wt) {
    int idx = blockIdx.x * 256 + threadIdx.x;
    if (idx >= 3 * 16384) return;
    int which = idx >> 14, e = idx & 16383;
    int k = e >> 7, n = e & 127;
    const float* W = (which == 0) ? W0 : ((which == 1) ? W1 : W2);
    wt[which * 16384 + n * 128 + k] = (__bf16)W[k * 128 + n];
}

// ---------------- pass 1: block-local counting sort of edges by dst bucket ----------------
// Output: staging[bucket region] packed entries ((dst&255)<<24)|src, grouped by bucket.
__global__ __launch_bounds__(512) void binsort(const int* __restrict__ ei,
                                               int* __restrict__ gcur,
                                               int* __restrict__ staging) {
    __shared__ int hist[512];
    __shared__ int hscan[512];
    __shared__ int cur[512];
    __shared__ int gofs[512];
    __shared__ uint2 lbuf[CHUNK];   // 64 KB
    int t = threadIdx.x;
    int base = blockIdx.x * CHUNK;

    hist[t] = 0;
    __syncthreads();
    // phase A: histogram dst buckets
    for (int i = t; i < CHUNK; i += 512)
        atomicAdd(&hist[ei[N_EDGES + base + i] >> 8], 1);
    __syncthreads();
    hscan[t] = hist[t];
    __syncthreads();
    // inclusive Hillis-Steele scan over 512
    for (int off = 1; off < 512; off <<= 1) {
        int v = (t >= off) ? hscan[t - off] : 0;
        __syncthreads();
        hscan[t] += v;
        __syncthreads();
    }
    int ex = hscan[t] - hist[t];   // exclusive prefix
    cur[t] = ex;
    if (t < NB && hist[t] > 0) {
        int gb = atomicAdd(&gcur[t], hist[t]);
        gofs[t] = t * CAPB + gb - ex;
    }
    __syncthreads();
    // phase B: scatter into locally-sorted LDS buffer
    for (int i = t; i < CHUNK; i += 512) {
        unsigned src = (unsigned)ei[base + i];
        unsigned dst = (unsigned)ei[N_EDGES + base + i];
        int p = atomicAdd(&cur[dst >> 8], 1);
        lbuf[p] = make_uint2(src, dst);
    }
    __syncthreads();
    // phase C: grouped, mostly-coalesced global writes
    for (int i = t; i < CHUNK; i += 512) {
        uint2 v = lbuf[i];
        int b = (int)(v.y >> 8);
        staging[gofs[b] + i] = (int)(((v.y & 255u) << 24) | v.x);
    }
}

// ---------------- pass 2: per-bucket srclist build in LDS, streamed out ----------------
__global__ __launch_bounds__(256) void build_csr(const int* __restrict__ gcur,
                                                 const int* __restrict__ staging,
                                                 int* __restrict__ srclist,
                                                 int* __restrict__ cnt,
                                                 float* __restrict__ dinv) {
    __shared__ int slots[256 * CAP];   // 64 KB
    __shared__ int lcnt[256];
    int t = threadIdx.x, b = blockIdx.x;
    lcnt[t] = 0;
    __syncthreads();
    int cb = gcur[b];
    if (cb > CAPB) cb = CAPB;
    const int* st = staging + b * CAPB;
    for (int i = t; i < cb; i += 256) {
        int v = st[i];
        int ld = ((unsigned)v) >> 24;
        int s = v & 0xFFFFFF;
        int p = atomicAdd(&lcnt[ld], 1);
        if (p < CAP) slots[ld * CAP + p] = s;
    }
    __syncthreads();
    // stream the whole 64 KB slab out (garbage beyond deg is never read)
    int4* d4 = (int4*)(srclist + (size_t)b * 256 * CAP);
    const int4* s4 = (const int4*)slots;
    for (int j = t; j < 256 * CAP / 4; j += 256) d4[j] = s4[j];
    int node = b * 256 + t;
    if (node < N_NODES) {
        int c = lcnt[t];
        cnt[node] = c;
        dinv[node] = rsqrtf((float)c + 1.0f);
    }
}

// ---------------- GEMM: H[100000,128] = A[100000,128] @ W[128,128], bf16 MFMA ----------------
template <bool A_IS_F32>
__global__ __launch_bounds__(256) void gemm128(const void* __restrict__ Ap,
                                               const __bf16* __restrict__ Wt,
                                               __bf16* __restrict__ H) {
    int wid = (blockIdx.x * 256 + threadIdx.x) >> 6;
    if (wid >= N_NODES / 16) return;   // 6250 waves exactly
    int lane = threadIdx.x & 63;
    int m = lane & 15, q = lane >> 4;
    int rowbase = wid * 16;

    f32x4 acc[8] = {};

#pragma unroll
    for (int ks = 0; ks < 4; ++ks) {
        bf16x8 a;
        if (A_IS_F32) {
            const float* A = (const float*)Ap + (size_t)(rowbase + m) * 128 + ks * 32 + q * 8;
            f32x4 v0 = *(const f32x4*)A;
            f32x4 v1 = *(const f32x4*)(A + 4);
            a[0] = (__bf16)v0[0]; a[1] = (__bf16)v0[1];
            a[2] = (__bf16)v0[2]; a[3] = (__bf16)v0[3];
            a[4] = (__bf16)v1[0]; a[5] = (__bf16)v1[1];
            a[6] = (__bf16)v1[2]; a[7] = (__bf16)v1[3];
        } else {
            a = *(const bf16x8*)((const __bf16*)Ap + (size_t)(rowbase + m) * 128 + ks * 32 + q * 8);
        }
#pragma unroll
        for (int tj = 0; tj < 8; ++tj) {
            bf16x8 b = *(const bf16x8*)(Wt + (tj * 16 + m) * 128 + ks * 32 + q * 8);
            acc[tj] = __builtin_amdgcn_mfma_f32_16x16x32_bf16(a, b, acc[tj], 0, 0, 0);
        }
    }

    // C/D layout: col = lane&15, row = (lane>>4)*4 + reg
#pragma unroll
    for (int tj = 0; tj < 8; ++tj) {
#pragma unroll
        for (int r = 0; r < 4; ++r) {
            int row = rowbase + q * 4 + r;
            H[(size_t)row * 128 + tj * 16 + m] = (__bf16)acc[tj][r];
        }
    }
}

// ---------------- aggregation: one wave per dst node, 4 edges/iter ----------------
template <bool RELU>
__global__ __launch_bounds__(256) void aggregate(const __bf16* __restrict__ H,
                                                 const float* __restrict__ bias,
                                                 const float* __restrict__ dinv,
                                                 const int* __restrict__ cnt,
                                                 const int* __restrict__ srclist,
                                                 __bf16* __restrict__ X) {
    int node = blockIdx.x * 4 + (threadIdx.x >> 6);
    int lane = threadIdx.x & 63;
    int g = lane >> 4;
    int idx = lane & 15;
    float di = dinv[node];
    int deg = cnt[node];
    if (deg > CAP) deg = CAP;
    const int* lst = srclist + (size_t)node * CAP;

    float acc[8] = {0.f, 0.f, 0.f, 0.f, 0.f, 0.f, 0.f, 0.f};

    for (int e = 0; e < deg; e += 4) {
        int ee = e + g;
        bool act = ee < deg;
        int s = lst[act ? ee : e];
        float f = act ? di * dinv[s] : 0.f;
        bf16x8 v = *(const bf16x8*)(H + (size_t)s * 128 + idx * 8);
#pragma unroll
        for (int j = 0; j < 8; ++j) acc[j] += f * (float)v[j];
    }

#pragma unroll
    for (int j = 0; j < 8; ++j) {
        acc[j] += __shfl_xor(acc[j], 16);
        acc[j] += __shfl_xor(acc[j], 32);
    }

    bf16x8 hv = *(const bf16x8*)(H + (size_t)node * 128 + idx * 8);
    f32x4 b0 = *(const f32x4*)(bias + idx * 8);
    f32x4 b1 = *(const f32x4*)(bias + idx * 8 + 4);
    float dii = di * di;
    bf16x8 o;
#pragma unroll
    for (int j = 0; j < 8; ++j) {
        float bj = (j < 4) ? b0[j] : b1[j - 4];
        float t = acc[j] + dii * (float)hv[j] + bj;
        if (RELU) t = fmaxf(t, 0.f);
        o[j] = (__bf16)t;
    }
    if (g == 0) *(bf16x8*)(X + (size_t)node * 128 + idx * 8) = o;
}

// ---------------- mean-pool per graph + linear + softmax ----------------
__global__ __launch_bounds__(256) void pool_head(const __bf16* __restrict__ X,
                                                 const int* __restrict__ batch,
                                                 const float* __restrict__ linW,
                                                 const float* __restrict__ linb,
                                                 float* __restrict__ out) {
    __shared__ int bounds[2];
    __shared__ float red[256];
    __shared__ float pooled[128];
    int g = blockIdx.x, t = threadIdx.x;
    if (t < 2) {
        int target = g + t;
        int lo = 0, hi = N_NODES;
        while (lo < hi) {
            int mid = (lo + hi) >> 1;
            if (batch[mid] < target) lo = mid + 1; else hi = mid;
        }
        bounds[t] = lo;
    }
    __syncthreads();
    int start = bounds[0], end = bounds[1];
    int d = t & 127, half = t >> 7;
    float s = 0.f;
    for (int i = start + half; i < end; i += 2)
        s += (float)X[(size_t)i * 128 + d];
    red[t] = s;
    __syncthreads();
    if (t < 128) {
        float c = (float)(end - start);
        pooled[d] = (red[t] + red[t + 128]) / fmaxf(c, 1.f);
    }
    __syncthreads();
    if (t == 0) {
        float lg[N_CLS];
        float mx = -1e30f;
        for (int c = 0; c < N_CLS; ++c) {
            float l = linb[c];
            for (int k = 0; k < 128; ++k) l += pooled[k] * linW[k * N_CLS + c];
            lg[c] = l;
            mx = fmaxf(mx, l);
        }
        float ssum = 0.f;
        for (int c = 0; c < N_CLS; ++c) { lg[c] = expf(lg[c] - mx); ssum += lg[c]; }
        for (int c = 0; c < N_CLS; ++c) out[g * N_CLS + c] = lg[c] / ssum;
    }
}

extern "C" void kernel_launch(void* const* d_in, const int* in_sizes, int n_in,
                              void* d_out, int out_size, void* d_ws, size_t ws_size,
                              hipStream_t stream) {
    const float* x     = (const float*)d_in[0];
    const int*   ei    = (const int*)d_in[1];
    const int*   batch = (const int*)d_in[2];
    const float* W0    = (const float*)d_in[3];
    const float* b0    = (const float*)d_in[4];
    const float* W1    = (const float*)d_in[5];
    const float* b1    = (const float*)d_in[6];
    const float* W2    = (const float*)d_in[7];
    const float* b2    = (const float*)d_in[8];
    const float* linW  = (const float*)d_in[9];
    const float* linb  = (const float*)d_in[10];

    char* ws = (char*)d_ws;
    int*    gcur    = (int*)(ws + 0);             // 2048 B (391 used)
    float*  dinv    = (float*)(ws + 2048);        // 400000 B
    int*    cnt     = (int*)(ws + 402048);        // 400000 B
    __bf16* wt      = (__bf16*)(ws + 802048);     // 98304 B
    int*    srclist = (int*)(ws + 900352);        // 100096*64*4 = 25624576 B
    __bf16* hbuf    = (__bf16*)(ws + 26524928);   // 25.6 MB
    int*    staging = (int*)(ws + 26524928);      // 7.2 MB, aliases hbuf (dead before gemm)
    __bf16* xbuf    = (__bf16*)(ws + 52124928);   // 25.6 MB  (total 77.7 MB)

    hipMemsetAsync(gcur, 0, 2048, stream);

    prepW<<<192, 256, 0, stream>>>(W0, W1, W2, wt);
    binsort<<<200, 512, 0, stream>>>(ei, gcur, staging);
    build_csr<<<NB, 256, 0, stream>>>(gcur, staging, srclist, cnt, dinv);

    // Layer 0
    gemm128<true><<<1563, 256, 0, stream>>>(x, wt, hbuf);
    aggregate<true><<<N_NODES / 4, 256, 0, stream>>>(hbuf, b0, dinv, cnt, srclist, xbuf);
    // Layer 1
    gemm128<false><<<1563, 256, 0, stream>>>(xbuf, wt + 16384, hbuf);
    aggregate<true><<<N_NODES / 4, 256, 0, stream>>>(hbuf, b1, dinv, cnt, srclist, xbuf);
    // Layer 2 (no relu)
    gemm128<false><<<1563, 256, 0, stream>>>(xbuf, wt + 32768, hbuf);
    aggregate<false><<<N_NODES / 4, 256, 0, stream>>>(hbuf, b2, dinv, cnt, srclist, xbuf);

    pool_head<<<N_GRAPHS, 256, 0, stream>>>(xbuf, batch, linW, linb, (float*)d_out);
}

// Round 4
// 524.504 us; speedup vs baseline: 1.7103x; 1.1504x over previous
//
#include <hip/hip_runtime.h>
#include <hip/hip_bf16.h>

#define N_NODES  100000
#define N_EDGES  1600000
#define D_FEAT   128
#define N_GRAPHS 128
#define N_CLS    10
#define CAP      64

#define NB       391      // buckets of 256 dst nodes (391*256 = 100096)
#define CAPB     4608     // staging capacity per bucket (mean 4096, +8 sigma)
#define CHUNK    8000     // edges per binsort block (200 * 8000 = 1.6M)
#define PCHUNK   128      // nodes per pool_partial block

typedef __bf16 bf16x8 __attribute__((ext_vector_type(8)));
typedef __bf16 bf16x2 __attribute__((ext_vector_type(2)));
typedef float  f32x4  __attribute__((ext_vector_type(4)));

// ---------------- W transpose + bf16 convert (Wt[n][k]) ----------------
__global__ __launch_bounds__(256) void prepW(const float* __restrict__ W0,
                                             const float* __restrict__ W1,
                                             const float* __restrict__ W2,
                                             __bf16* __restrict__ wt) {
    int idx = blockIdx.x * 256 + threadIdx.x;
    if (idx >= 3 * 16384) return;
    int which = idx >> 14, e = idx & 16383;
    int k = e >> 7, n = e & 127;
    const float* W = (which == 0) ? W0 : ((which == 1) ? W1 : W2);
    wt[which * 16384 + n * 128 + k] = (__bf16)W[k * 128 + n];
}

// ---------------- pass 1: block-local counting sort of edges by dst bucket ----------------
__global__ __launch_bounds__(512) void binsort(const int* __restrict__ ei,
                                               int* __restrict__ gcur,
                                               int* __restrict__ staging) {
    __shared__ int hist[512];
    __shared__ int hscan[512];
    __shared__ int cur[512];
    __shared__ int gofs[512];
    __shared__ uint2 lbuf[CHUNK];   // 64 KB
    int t = threadIdx.x;
    int base = blockIdx.x * CHUNK;

    hist[t] = 0;
    __syncthreads();
    for (int i = t; i < CHUNK; i += 512)
        atomicAdd(&hist[ei[N_EDGES + base + i] >> 8], 1);
    __syncthreads();
    hscan[t] = hist[t];
    __syncthreads();
    for (int off = 1; off < 512; off <<= 1) {
        int v = (t >= off) ? hscan[t - off] : 0;
        __syncthreads();
        hscan[t] += v;
        __syncthreads();
    }
    int ex = hscan[t] - hist[t];
    cur[t] = ex;
    if (t < NB && hist[t] > 0) {
        int gb = atomicAdd(&gcur[t], hist[t]);
        gofs[t] = t * CAPB + gb - ex;
    }
    __syncthreads();
    for (int i = t; i < CHUNK; i += 512) {
        unsigned src = (unsigned)ei[base + i];
        unsigned dst = (unsigned)ei[N_EDGES + base + i];
        int p = atomicAdd(&cur[dst >> 8], 1);
        lbuf[p] = make_uint2(src, dst);
    }
    __syncthreads();
    for (int i = t; i < CHUNK; i += 512) {
        uint2 v = lbuf[i];
        int b = (int)(v.y >> 8);
        staging[gofs[b] + i] = (int)(((v.y & 255u) << 24) | v.x);
    }
}

// ---------------- pass 2: per-bucket srclist build in LDS, streamed out ----------------
__global__ __launch_bounds__(256) void build_csr(const int* __restrict__ gcur,
                                                 const int* __restrict__ staging,
                                                 int* __restrict__ srclist,
                                                 int* __restrict__ cnt,
                                                 float* __restrict__ dinv) {
    __shared__ int slots[256 * CAP];   // 64 KB
    __shared__ int lcnt[256];
    int t = threadIdx.x, b = blockIdx.x;
    lcnt[t] = 0;
    __syncthreads();
    int cb = gcur[b];
    if (cb > CAPB) cb = CAPB;
    const int* st = staging + b * CAPB;
    for (int i = t; i < cb; i += 256) {
        int v = st[i];
        int ld = ((unsigned)v) >> 24;
        int s = v & 0xFFFFFF;
        int p = atomicAdd(&lcnt[ld], 1);
        if (p < CAP) slots[ld * CAP + p] = s;
    }
    __syncthreads();
    int4* d4 = (int4*)(srclist + (size_t)b * 256 * CAP);
    const int4* s4 = (const int4*)slots;
    for (int j = t; j < 256 * CAP / 4; j += 256) d4[j] = s4[j];
    int node = b * 256 + t;
    if (node < N_NODES) {
        int c = lcnt[t];
        cnt[node] = c;
        dinv[node] = rsqrtf((float)c + 1.0f);
    }
}

// ---------------- GEMM: H[100000,128] = A[100000,128] @ W[128,128], bf16 MFMA ----------------
template <bool A_IS_F32>
__global__ __launch_bounds__(256) void gemm128(const void* __restrict__ Ap,
                                               const __bf16* __restrict__ Wt,
                                               __bf16* __restrict__ H) {
    int wid = (blockIdx.x * 256 + threadIdx.x) >> 6;
    if (wid >= N_NODES / 16) return;
    int lane = threadIdx.x & 63;
    int m = lane & 15, q = lane >> 4;
    int rowbase = wid * 16;

    f32x4 acc[8] = {};

#pragma unroll
    for (int ks = 0; ks < 4; ++ks) {
        bf16x8 a;
        if (A_IS_F32) {
            const float* A = (const float*)Ap + (size_t)(rowbase + m) * 128 + ks * 32 + q * 8;
            f32x4 v0 = *(const f32x4*)A;
            f32x4 v1 = *(const f32x4*)(A + 4);
            a[0] = (__bf16)v0[0]; a[1] = (__bf16)v0[1];
            a[2] = (__bf16)v0[2]; a[3] = (__bf16)v0[3];
            a[4] = (__bf16)v1[0]; a[5] = (__bf16)v1[1];
            a[6] = (__bf16)v1[2]; a[7] = (__bf16)v1[3];
        } else {
            a = *(const bf16x8*)((const __bf16*)Ap + (size_t)(rowbase + m) * 128 + ks * 32 + q * 8);
        }
#pragma unroll
        for (int tj = 0; tj < 8; ++tj) {
            bf16x8 b = *(const bf16x8*)(Wt + (tj * 16 + m) * 128 + ks * 32 + q * 8);
            acc[tj] = __builtin_amdgcn_mfma_f32_16x16x32_bf16(a, b, acc[tj], 0, 0, 0);
        }
    }

#pragma unroll
    for (int tj = 0; tj < 8; ++tj) {
#pragma unroll
        for (int r = 0; r < 4; ++r) {
            int row = rowbase + q * 4 + r;
            H[(size_t)row * 128 + tj * 16 + m] = (__bf16)acc[tj][r];
        }
    }
}

// ---------------- aggregation: one wave per dst node, 4 edges/iter ----------------
template <bool RELU>
__global__ __launch_bounds__(256) void aggregate(const __bf16* __restrict__ H,
                                                 const float* __restrict__ bias,
                                                 const float* __restrict__ dinv,
                                                 const int* __restrict__ cnt,
                                                 const int* __restrict__ srclist,
                                                 __bf16* __restrict__ X) {
    int node = blockIdx.x * 4 + (threadIdx.x >> 6);
    int lane = threadIdx.x & 63;
    int g = lane >> 4;
    int idx = lane & 15;
    float di = dinv[node];
    int deg = cnt[node];
    if (deg > CAP) deg = CAP;
    const int* lst = srclist + (size_t)node * CAP;

    float acc[8] = {0.f, 0.f, 0.f, 0.f, 0.f, 0.f, 0.f, 0.f};

    for (int e = 0; e < deg; e += 4) {
        int ee = e + g;
        bool act = ee < deg;
        int s = lst[act ? ee : e];
        float f = act ? di * dinv[s] : 0.f;
        bf16x8 v = *(const bf16x8*)(H + (size_t)s * 128 + idx * 8);
#pragma unroll
        for (int j = 0; j < 8; ++j) acc[j] += f * (float)v[j];
    }

#pragma unroll
    for (int j = 0; j < 8; ++j) {
        acc[j] += __shfl_xor(acc[j], 16);
        acc[j] += __shfl_xor(acc[j], 32);
    }

    bf16x8 hv = *(const bf16x8*)(H + (size_t)node * 128 + idx * 8);
    f32x4 b0 = *(const f32x4*)(bias + idx * 8);
    f32x4 b1 = *(const f32x4*)(bias + idx * 8 + 4);
    float dii = di * di;
    bf16x8 o;
#pragma unroll
    for (int j = 0; j < 8; ++j) {
        float bj = (j < 4) ? b0[j] : b1[j - 4];
        float t = acc[j] + dii * (float)hv[j] + bj;
        if (RELU) t = fmaxf(t, 0.f);
        o[j] = (__bf16)t;
    }
    if (g == 0) *(bf16x8*)(X + (size_t)node * 128 + idx * 8) = o;
}

// ---------------- pooling stage 1: per-chunk fp32 partial sums, atomic flush ----------------
__global__ __launch_bounds__(256) void pool_partial(const __bf16* __restrict__ X,
                                                    const int* __restrict__ batch,
                                                    float* __restrict__ sums) {
    int t = threadIdx.x;
    int d = t & 127, half = t >> 7;
    int start = blockIdx.x * PCHUNK;
    int end = start + PCHUNK;
    if (end > N_NODES) end = N_NODES;
    float acc = 0.f;
    int curg = -1;
    for (int i = start + half; i < end; i += 2) {
        int g = batch[i];
        if (g != curg) {
            if (curg >= 0) atomicAdd(&sums[curg * 128 + d], acc);
            acc = 0.f;
            curg = g;
        }
        acc += (float)X[(size_t)i * 128 + d];
    }
    if (curg >= 0) atomicAdd(&sums[curg * 128 + d], acc);
}

// ---------------- pooling stage 2: divide, linear, softmax ----------------
__global__ __launch_bounds__(64) void pool_final(const float* __restrict__ sums,
                                                 const int* __restrict__ batch,
                                                 const float* __restrict__ linW,
                                                 const float* __restrict__ linb,
                                                 float* __restrict__ out) {
    int g = blockIdx.x, lane = threadIdx.x;
    // counts via two binary searches (wave-uniform)
    int bnd[2];
#pragma unroll
    for (int k = 0; k < 2; ++k) {
        int target = g + k;
        int lo = 0, hi = N_NODES;
        while (lo < hi) {
            int mid = (lo + hi) >> 1;
            if (batch[mid] < target) lo = mid + 1; else hi = mid;
        }
        bnd[k] = lo;
    }
    float c = fmaxf((float)(bnd[1] - bnd[0]), 1.f);
    float p0 = sums[g * 128 + lane] / c;
    float p1 = sums[g * 128 + 64 + lane] / c;

    float lg[N_CLS];
#pragma unroll
    for (int cc = 0; cc < N_CLS; ++cc) {
        float v = p0 * linW[lane * N_CLS + cc] + p1 * linW[(lane + 64) * N_CLS + cc];
#pragma unroll
        for (int off = 1; off < 64; off <<= 1) v += __shfl_xor(v, off);
        lg[cc] = v + linb[cc];
    }
    float mx = -1e30f;
#pragma unroll
    for (int cc = 0; cc < N_CLS; ++cc) mx = fmaxf(mx, lg[cc]);
    float ssum = 0.f;
#pragma unroll
    for (int cc = 0; cc < N_CLS; ++cc) { lg[cc] = __expf(lg[cc] - mx); ssum += lg[cc]; }
    if (lane < N_CLS) out[g * N_CLS + lane] = lg[lane] / ssum;
}

extern "C" void kernel_launch(void* const* d_in, const int* in_sizes, int n_in,
                              void* d_out, int out_size, void* d_ws, size_t ws_size,
                              hipStream_t stream) {
    const float* x     = (const float*)d_in[0];
    const int*   ei    = (const int*)d_in[1];
    const int*   batch = (const int*)d_in[2];
    const float* W0    = (const float*)d_in[3];
    const float* b0    = (const float*)d_in[4];
    const float* W1    = (const float*)d_in[5];
    const float* b1    = (const float*)d_in[6];
    const float* W2    = (const float*)d_in[7];
    const float* b2    = (const float*)d_in[8];
    const float* linW  = (const float*)d_in[9];
    const float* linb  = (const float*)d_in[10];

    char* ws = (char*)d_ws;
    int*    gcur    = (int*)(ws + 0);             // 2048 B
    float*  sums    = (float*)(ws + 2048);        // 65536 B (128 graphs x 128 dims fp32)
    float*  dinv    = (float*)(ws + 67584);       // 400000 B
    int*    cnt     = (int*)(ws + 467584);        // 400000 B
    __bf16* wt      = (__bf16*)(ws + 867584);     // 98304 B
    int*    srclist = (int*)(ws + 965888);        // 25624576 B
    __bf16* hbuf    = (__bf16*)(ws + 26590464);   // 25.6 MB
    int*    staging = (int*)(ws + 26590464);      // 7.2 MB, aliases hbuf (dead before gemm)
    __bf16* xbuf    = (__bf16*)(ws + 52190464);   // 25.6 MB (total ~77.8 MB)

    hipMemsetAsync(ws, 0, 67584, stream);         // gcur + sums

    prepW<<<192, 256, 0, stream>>>(W0, W1, W2, wt);
    binsort<<<200, 512, 0, stream>>>(ei, gcur, staging);
    build_csr<<<NB, 256, 0, stream>>>(gcur, staging, srclist, cnt, dinv);

    // Layer 0
    gemm128<true><<<1563, 256, 0, stream>>>(x, wt, hbuf);
    aggregate<true><<<N_NODES / 4, 256, 0, stream>>>(hbuf, b0, dinv, cnt, srclist, xbuf);
    // Layer 1
    gemm128<false><<<1563, 256, 0, stream>>>(xbuf, wt + 16384, hbuf);
    aggregate<true><<<N_NODES / 4, 256, 0, stream>>>(hbuf, b1, dinv, cnt, srclist, xbuf);
    // Layer 2 (no relu)
    gemm128<false><<<1563, 256, 0, stream>>>(xbuf, wt + 32768, hbuf);
    aggregate<false><<<N_NODES / 4, 256, 0, stream>>>(hbuf, b2, dinv, cnt, srclist, xbuf);

    pool_partial<<<(N_NODES + PCHUNK - 1) / PCHUNK, 256, 0, stream>>>(xbuf, batch, sums);
    pool_final<<<N_GRAPHS, 64, 0, stream>>>(sums, batch, linW, linb, (float*)d_out);
}

// Round 5
// 426.067 us; speedup vs baseline: 2.1055x; 1.2310x over previous
//
#include <hip/hip_runtime.h>
#include <hip/hip_bf16.h>

#define N_NODES  100000
#define N_EDGES  1600000
#define D_FEAT   128
#define N_GRAPHS 128
#define N_CLS    10
#define CAP      64
#define ZROW     100000   // dedicated all-zero fp8 row

#define NB       391      // buckets of 256 dst nodes (391*256 = 100096)
#define CAPB     4608     // staging capacity per bucket
#define CHUNK    8000     // edges per binsort block
#define PCHUNK   128      // nodes per pool_partial block

typedef __bf16 bf16x8 __attribute__((ext_vector_type(8)));
typedef float  f32x4  __attribute__((ext_vector_type(4)));
typedef float  f32x2  __attribute__((ext_vector_type(2)));

// ---------------- W transpose + bf16 convert (Wt[n][k]) + zero-row init ----------------
__global__ __launch_bounds__(256) void prepW(const float* __restrict__ W0,
                                             const float* __restrict__ W1,
                                             const float* __restrict__ W2,
                                             __bf16* __restrict__ wt,
                                             unsigned char* __restrict__ Hs) {
    int idx = blockIdx.x * 256 + threadIdx.x;
    if (blockIdx.x == 0 && threadIdx.x < 32)
        ((unsigned int*)(Hs + (size_t)ZROW * 128))[threadIdx.x] = 0u;
    if (idx >= 3 * 16384) return;
    int which = idx >> 14, e = idx & 16383;
    int k = e >> 7, n = e & 127;
    const float* W = (which == 0) ? W0 : ((which == 1) ? W1 : W2);
    wt[which * 16384 + n * 128 + k] = (__bf16)W[k * 128 + n];
}

// ---------------- pass 1: block-local counting sort of edges by dst bucket ----------------
__global__ __launch_bounds__(512) void binsort(const int* __restrict__ ei,
                                               int* __restrict__ gcur,
                                               int* __restrict__ staging) {
    __shared__ int hist[512];
    __shared__ int hscan[512];
    __shared__ int cur[512];
    __shared__ int gofs[512];
    __shared__ uint2 lbuf[CHUNK];   // 64 KB
    int t = threadIdx.x;
    int base = blockIdx.x * CHUNK;

    hist[t] = 0;
    __syncthreads();
    for (int i = t; i < CHUNK; i += 512)
        atomicAdd(&hist[ei[N_EDGES + base + i] >> 8], 1);
    __syncthreads();
    hscan[t] = hist[t];
    __syncthreads();
    for (int off = 1; off < 512; off <<= 1) {
        int v = (t >= off) ? hscan[t - off] : 0;
        __syncthreads();
        hscan[t] += v;
        __syncthreads();
    }
    int ex = hscan[t] - hist[t];
    cur[t] = ex;
    if (t < NB && hist[t] > 0) {
        int gb = atomicAdd(&gcur[t], hist[t]);
        gofs[t] = t * CAPB + gb - ex;
    }
    __syncthreads();
    for (int i = t; i < CHUNK; i += 512) {
        unsigned src = (unsigned)ei[base + i];
        unsigned dst = (unsigned)ei[N_EDGES + base + i];
        int p = atomicAdd(&cur[dst >> 8], 1);
        lbuf[p] = make_uint2(src, dst);
    }
    __syncthreads();
    for (int i = t; i < CHUNK; i += 512) {
        uint2 v = lbuf[i];
        int b = (int)(v.y >> 8);
        staging[gofs[b] + i] = (int)(((v.y & 255u) << 24) | v.x);
    }
}

// ---------------- pass 2: per-bucket srclist build in LDS, streamed out ----------------
__global__ __launch_bounds__(256) void build_csr(const int* __restrict__ gcur,
                                                 const int* __restrict__ staging,
                                                 int* __restrict__ srclist,
                                                 int* __restrict__ cnt,
                                                 float* __restrict__ dinv) {
    __shared__ int slots[256 * CAP];   // 64 KB
    __shared__ int lcnt[256];
    int t = threadIdx.x, b = blockIdx.x;
    lcnt[t] = 0;
    __syncthreads();
    int cb = gcur[b];
    if (cb > CAPB) cb = CAPB;
    const int* st = staging + b * CAPB;
    for (int i = t; i < cb; i += 256) {
        int v = st[i];
        int ld = ((unsigned)v) >> 24;
        int s = v & 0xFFFFFF;
        int p = atomicAdd(&lcnt[ld], 1);
        if (p < CAP) slots[ld * CAP + p] = s;
    }
    __syncthreads();
    int4* d4 = (int4*)(srclist + (size_t)b * 256 * CAP);
    const int4* s4 = (const int4*)slots;
    for (int j = t; j < 256 * CAP / 4; j += 256) d4[j] = s4[j];
    int node = b * 256 + t;
    if (node < N_NODES) {
        int c = lcnt[t];
        cnt[node] = c;
        dinv[node] = rsqrtf((float)c + 1.0f);
    }
}

// ---------------- GEMM: Hs[row] = fp8(dinv[row] * (A @ W)[row]), bf16 MFMA ----------------
template <bool A_IS_F32>
__global__ __launch_bounds__(256) void gemm128(const void* __restrict__ Ap,
                                               const __bf16* __restrict__ Wt,
                                               const float* __restrict__ dinv,
                                               unsigned char* __restrict__ Hs) {
    int wid = (blockIdx.x * 256 + threadIdx.x) >> 6;
    if (wid >= N_NODES / 16) return;
    int lane = threadIdx.x & 63;
    int m = lane & 15, q = lane >> 4;
    int rowbase = wid * 16;

    f32x4 acc[8] = {};

#pragma unroll
    for (int ks = 0; ks < 4; ++ks) {
        bf16x8 a;
        if (A_IS_F32) {
            const float* A = (const float*)Ap + (size_t)(rowbase + m) * 128 + ks * 32 + q * 8;
            f32x4 v0 = *(const f32x4*)A;
            f32x4 v1 = *(const f32x4*)(A + 4);
            a[0] = (__bf16)v0[0]; a[1] = (__bf16)v0[1];
            a[2] = (__bf16)v0[2]; a[3] = (__bf16)v0[3];
            a[4] = (__bf16)v1[0]; a[5] = (__bf16)v1[1];
            a[6] = (__bf16)v1[2]; a[7] = (__bf16)v1[3];
        } else {
            a = *(const bf16x8*)((const __bf16*)Ap + (size_t)(rowbase + m) * 128 + ks * 32 + q * 8);
        }
#pragma unroll
        for (int tj = 0; tj < 8; ++tj) {
            bf16x8 b = *(const bf16x8*)(Wt + (tj * 16 + m) * 128 + ks * 32 + q * 8);
            acc[tj] = __builtin_amdgcn_mfma_f32_16x16x32_bf16(a, b, acc[tj], 0, 0, 0);
        }
    }

    // C/D layout: col = tj*16 + m, row = rowbase + q*4 + r
    float dv[4];
#pragma unroll
    for (int r = 0; r < 4; ++r) dv[r] = dinv[rowbase + q * 4 + r];
#pragma unroll
    for (int tj = 0; tj < 8; ++tj) {
#pragma unroll
        for (int r = 0; r < 4; ++r) {
            float val = acc[tj][r] * dv[r];
            int pk = __builtin_amdgcn_cvt_pk_fp8_f32(val, val, 0, false);
            Hs[(size_t)(rowbase + q * 4 + r) * 128 + tj * 16 + m] = (unsigned char)(pk & 0xFF);
        }
    }
}

// ---------------- aggregation: one wave per dst node, fp8 gather, pipelined ----------------
// lanes: g = lane>>4 (edge slot), idx = lane&15 (dims idx*8..idx*8+7, 8 B/lane fp8)
template <bool RELU>
__global__ __launch_bounds__(256) void aggregate(const unsigned char* __restrict__ Hs,
                                                 const float* __restrict__ bias,
                                                 const float* __restrict__ dinv,
                                                 const int* __restrict__ cnt,
                                                 const int* __restrict__ srclist,
                                                 __bf16* __restrict__ X) {
    int node = blockIdx.x * 4 + (threadIdx.x >> 6);
    int lane = threadIdx.x & 63;
    int g = lane >> 4;
    int idx = lane & 15;
    float di = dinv[node];
    int deg = cnt[node];
    if (deg > CAP) deg = CAP;
    const int* lst = srclist + (size_t)node * CAP;

    float acc[8] = {0.f, 0.f, 0.f, 0.f, 0.f, 0.f, 0.f, 0.f};

    // depth-1 software pipeline
    int s = (g < deg) ? lst[g] : ZROW;
    uint2 v = *(const uint2*)(Hs + (size_t)s * 128 + idx * 8);
    for (int e = 0; e < deg; e += 4) {
        int en = e + 4 + g;
        int sn = (en < deg) ? lst[en & 63] : ZROW;
        uint2 vn = *(const uint2*)(Hs + (size_t)sn * 128 + idx * 8);
        f32x2 p0 = __builtin_amdgcn_cvt_pk_f32_fp8(v.x, false);
        f32x2 p1 = __builtin_amdgcn_cvt_pk_f32_fp8(v.x, true);
        f32x2 p2 = __builtin_amdgcn_cvt_pk_f32_fp8(v.y, false);
        f32x2 p3 = __builtin_amdgcn_cvt_pk_f32_fp8(v.y, true);
        acc[0] += p0.x; acc[1] += p0.y; acc[2] += p1.x; acc[3] += p1.y;
        acc[4] += p2.x; acc[5] += p2.y; acc[6] += p3.x; acc[7] += p3.y;
        v = vn;
    }

    // reduce across the 4 edge-groups
#pragma unroll
    for (int j = 0; j < 8; ++j) {
        acc[j] += __shfl_xor(acc[j], 16);
        acc[j] += __shfl_xor(acc[j], 32);
    }

    // self-loop term: + Hs[node] (already scaled by dinv[node])
    uint2 hv = *(const uint2*)(Hs + (size_t)node * 128 + idx * 8);
    f32x2 q0 = __builtin_amdgcn_cvt_pk_f32_fp8(hv.x, false);
    f32x2 q1 = __builtin_amdgcn_cvt_pk_f32_fp8(hv.x, true);
    f32x2 q2 = __builtin_amdgcn_cvt_pk_f32_fp8(hv.y, false);
    f32x2 q3 = __builtin_amdgcn_cvt_pk_f32_fp8(hv.y, true);
    acc[0] += q0.x; acc[1] += q0.y; acc[2] += q1.x; acc[3] += q1.y;
    acc[4] += q2.x; acc[5] += q2.y; acc[6] += q3.x; acc[7] += q3.y;

    f32x4 b0 = *(const f32x4*)(bias + idx * 8);
    f32x4 b1 = *(const f32x4*)(bias + idx * 8 + 4);
    bf16x8 o;
#pragma unroll
    for (int j = 0; j < 8; ++j) {
        float bj = (j < 4) ? b0[j] : b1[j - 4];
        float t = di * acc[j] + bj;
        if (RELU) t = fmaxf(t, 0.f);
        o[j] = (__bf16)t;
    }
    if (g == 0) *(bf16x8*)(X + (size_t)node * 128 + idx * 8) = o;
}

// ---------------- pooling stage 1: per-chunk fp32 partial sums, atomic flush ----------------
__global__ __launch_bounds__(256) void pool_partial(const __bf16* __restrict__ X,
                                                    const int* __restrict__ batch,
                                                    float* __restrict__ sums) {
    int t = threadIdx.x;
    int d = t & 127, half = t >> 7;
    int start = blockIdx.x * PCHUNK;
    int end = start + PCHUNK;
    if (end > N_NODES) end = N_NODES;
    float acc = 0.f;
    int curg = -1;
    for (int i = start + half; i < end; i += 2) {
        int g = batch[i];
        if (g != curg) {
            if (curg >= 0) atomicAdd(&sums[curg * 128 + d], acc);
            acc = 0.f;
            curg = g;
        }
        acc += (float)X[(size_t)i * 128 + d];
    }
    if (curg >= 0) atomicAdd(&sums[curg * 128 + d], acc);
}

// ---------------- pooling stage 2: divide, linear, softmax ----------------
__global__ __launch_bounds__(64) void pool_final(const float* __restrict__ sums,
                                                 const int* __restrict__ batch,
                                                 const float* __restrict__ linW,
                                                 const float* __restrict__ linb,
                                                 float* __restrict__ out) {
    int g = blockIdx.x, lane = threadIdx.x;
    int bnd[2];
#pragma unroll
    for (int k = 0; k < 2; ++k) {
        int target = g + k;
        int lo = 0, hi = N_NODES;
        while (lo < hi) {
            int mid = (lo + hi) >> 1;
            if (batch[mid] < target) lo = mid + 1; else hi = mid;
        }
        bnd[k] = lo;
    }
    float c = fmaxf((float)(bnd[1] - bnd[0]), 1.f);
    float p0 = sums[g * 128 + lane] / c;
    float p1 = sums[g * 128 + 64 + lane] / c;

    float lg[N_CLS];
#pragma unroll
    for (int cc = 0; cc < N_CLS; ++cc) {
        float v = p0 * linW[lane * N_CLS + cc] + p1 * linW[(lane + 64) * N_CLS + cc];
#pragma unroll
        for (int off = 1; off < 64; off <<= 1) v += __shfl_xor(v, off);
        lg[cc] = v + linb[cc];
    }
    float mx = -1e30f;
#pragma unroll
    for (int cc = 0; cc < N_CLS; ++cc) mx = fmaxf(mx, lg[cc]);
    float ssum = 0.f;
#pragma unroll
    for (int cc = 0; cc < N_CLS; ++cc) { lg[cc] = __expf(lg[cc] - mx); ssum += lg[cc]; }
    if (lane < N_CLS) out[g * N_CLS + lane] = lg[lane] / ssum;
}

extern "C" void kernel_launch(void* const* d_in, const int* in_sizes, int n_in,
                              void* d_out, int out_size, void* d_ws, size_t ws_size,
                              hipStream_t stream) {
    const float* x     = (const float*)d_in[0];
    const int*   ei    = (const int*)d_in[1];
    const int*   batch = (const int*)d_in[2];
    const float* W0    = (const float*)d_in[3];
    const float* b0    = (const float*)d_in[4];
    const float* W1    = (const float*)d_in[5];
    const float* b1    = (const float*)d_in[6];
    const float* W2    = (const float*)d_in[7];
    const float* b2    = (const float*)d_in[8];
    const float* linW  = (const float*)d_in[9];
    const float* linb  = (const float*)d_in[10];

    char* ws = (char*)d_ws;
    int*    gcur    = (int*)(ws + 0);             // 2048 B
    float*  sums    = (float*)(ws + 2048);        // 65536 B
    float*  dinv    = (float*)(ws + 67584);       // 400000 B
    int*    cnt     = (int*)(ws + 467584);        // 400000 B
    __bf16* wt      = (__bf16*)(ws + 867584);     // 98304 B
    int*    srclist = (int*)(ws + 965888);        // 25624576 B
    unsigned char* Hs = (unsigned char*)(ws + 26590464); // 100001*128 = 12.8 MB fp8
    int*    staging = (int*)(ws + 26590464);      // 7.2 MB, aliases Hs rows (dead before gemm)
    __bf16* xbuf    = (__bf16*)(ws + 52190464);   // 25.6 MB

    hipMemsetAsync(ws, 0, 67584, stream);         // gcur + sums

    prepW<<<192, 256, 0, stream>>>(W0, W1, W2, wt, Hs);   // also zeroes Hs[ZROW]
    binsort<<<200, 512, 0, stream>>>(ei, gcur, staging);
    build_csr<<<NB, 256, 0, stream>>>(gcur, staging, srclist, cnt, dinv);

    // Layer 0
    gemm128<true><<<1563, 256, 0, stream>>>(x, wt, dinv, Hs);
    aggregate<true><<<N_NODES / 4, 256, 0, stream>>>(Hs, b0, dinv, cnt, srclist, xbuf);
    // Layer 1
    gemm128<false><<<1563, 256, 0, stream>>>(xbuf, wt + 16384, dinv, Hs);
    aggregate<true><<<N_NODES / 4, 256, 0, stream>>>(Hs, b1, dinv, cnt, srclist, xbuf);
    // Layer 2 (no relu)
    gemm128<false><<<1563, 256, 0, stream>>>(xbuf, wt + 32768, dinv, Hs);
    aggregate<false><<<N_NODES / 4, 256, 0, stream>>>(Hs, b2, dinv, cnt, srclist, xbuf);

    pool_partial<<<(N_NODES + PCHUNK - 1) / PCHUNK, 256, 0, stream>>>(xbuf, batch, sums);
    pool_final<<<N_GRAPHS, 64, 0, stream>>>(sums, batch, linW, linb, (float*)d_out);
}